// Round 17
// baseline (91614.728 us; speedup 1.0000x reference)
//
#include <hip/hip_runtime.h>
#include <hip/hip_cooperative_groups.h>
#include <stdint.h>
#include <math.h>

namespace cg = cooperative_groups;
typedef unsigned int u32;

constexpr int kB = 512, kS = 128, kH = 512, kE = 256, kT = 100;
constexpr int kNG = 4 * kH; // 2048

// ---- ws layout (f32 elements) ----
constexpr size_t SZ_E = (size_t)kS * kB * kH; // 33,554,432
constexpr size_t OFF_EG  = 0;                              // EG [s][b][h]
constexpr size_t OFF_EP  = OFF_EG + SZ_E;                  // EP [s][b][h]
constexpr size_t OFF_U   = OFF_EP + SZ_E;
constexpr size_t OFF_P   = OFF_U + (size_t)kB * kS;
constexpr size_t OFF_QP  = OFF_P + (size_t)kB * kS;        // kB*kH
constexpr size_t OFF_GL  = OFF_QP + (size_t)kB * kH;       // kB*kH
constexpr size_t OFF_G   = OFF_GL + (size_t)kB * kH;       // kB*kNG
constexpr size_t OFF_HX  = OFF_G + (size_t)kB * kNG;       // kB*kH
constexpr size_t OFF_CX  = OFF_HX + (size_t)kB * kH;       // kB*kH
constexpr size_t OFF_DC  = OFF_CX + (size_t)kB * kH;       // kB*kE
constexpr size_t OFF_FM  = OFF_DC + (size_t)kB * kE;       // kB ints
constexpr size_t OFF_FMM = OFF_FM + kB;
constexpr size_t WS_FLOATS = OFF_FMM + kB;                 // ≈265 MiB (PROVEN available)

// ---------------- sentinel (bail only) ----------------
__global__ __launch_bounds__(256) void sentinel_k(float* __restrict__ outSel, float val) {
  int i = blockIdx.x * blockDim.x + threadIdx.x;
  if (i < kT * kB) outSel[i] = val;
}

// ---------------- threefry2x32 (exact JAX) ----------------
__device__ __forceinline__ u32 rotl32(u32 v, int d) { return (v << d) | (v >> (32 - d)); }

__device__ __forceinline__ void tf2x32(u32 k0, u32 k1, u32 x0, u32 x1, u32& o0, u32& o1) {
  u32 ks2 = k0 ^ k1 ^ 0x1BD11BDAu;
  x0 += k0; x1 += k1;
#define RND_(r) { x0 += x1; x1 = rotl32(x1, r); x1 ^= x0; }
  RND_(13) RND_(15) RND_(26) RND_(6)   x0 += k1;  x1 += ks2 + 1u;
  RND_(17) RND_(29) RND_(16) RND_(24)  x0 += ks2; x1 += k0 + 2u;
  RND_(13) RND_(15) RND_(26) RND_(6)   x0 += k0;  x1 += k1 + 3u;
  RND_(17) RND_(29) RND_(16) RND_(24)  x0 += k1;  x1 += ks2 + 4u;
  RND_(13) RND_(15) RND_(26) RND_(6)   x0 += ks2; x1 += k0 + 5u;
#undef RND_
  o0 = x0; o1 = x1;
}

__device__ __forceinline__ float sigf(float x) { return 1.0f / (1.0f + expf(-x)); }

// ------- E precompute (unchanged, proven) -------
__global__ __launch_bounds__(512) void precompute_e(const float* __restrict__ ctx,
                                                    const float* __restrict__ Wg,
                                                    const float* __restrict__ bg,
                                                    const float* __restrict__ Wp,
                                                    const float* __restrict__ bp,
                                                    float* __restrict__ EG,
                                                    float* __restrict__ EP) {
  __shared__ float ctxs[8][512];
  __shared__ float Wgs[512][33];
  __shared__ float Wps[512][33];
  const int tid = threadIdx.x;
  const size_t m0 = (size_t)blockIdx.x * 8;
  for (int idx = tid; idx < 8 * 512; idx += 512) {
    ctxs[idx >> 9][idx & 511] = ctx[(m0 + (idx >> 9)) * 512 + (idx & 511)];
  }
  float accg[8] = {}, accp[8] = {};
  for (int k0 = 0; k0 < 512; k0 += 32) {
    __syncthreads();
    for (int idx = tid; idx < 512 * 32; idx += 512) {
      int row = idx >> 5, kk = idx & 31;
      Wgs[row][kk] = Wg[(size_t)row * 512 + k0 + kk];
      Wps[row][kk] = Wp[(size_t)row * 512 + k0 + kk];
    }
    __syncthreads();
#pragma unroll 4
    for (int kk = 0; kk < 32; ++kk) {
      float wg = Wgs[tid][kk], wp = Wps[tid][kk];
#pragma unroll
      for (int mi = 0; mi < 8; ++mi) {
        float a = ctxs[mi][k0 + kk];
        accg[mi] = fmaf(a, wg, accg[mi]);
        accp[mi] = fmaf(a, wp, accp[mi]);
      }
    }
  }
  float bgv = bg[tid], bpv = bp[tid];
#pragma unroll
  for (int mi = 0; mi < 8; ++mi) {
    size_t m = m0 + mi;
    EG[m * 512 + tid] = accg[mi] + bgv;
    EP[m * 512 + tid] = accp[mi] + bpv;
  }
}

// =================== COOPERATIVE MEGAKERNEL (whole T loop) ===================
__global__ __launch_bounds__(512, 4) void mega_k(
    const float* __restrict__ EG, const float* __restrict__ EP, const float* __restrict__ Wi,
    const float* __restrict__ bi, const float* __restrict__ Wh, const float* __restrict__ bh,
    const float* __restrict__ gWq, const float* __restrict__ gbq, const float* __restrict__ gv,
    const float* __restrict__ pWq, const float* __restrict__ pbq, const float* __restrict__ pv,
    const float* __restrict__ emb, const int* __restrict__ counts,
    const float* __restrict__ dec_in, const float* __restrict__ hx0,
    const float* __restrict__ cx0, float* __restrict__ HX, float* __restrict__ CX,
    float* __restrict__ DC, float* __restrict__ QP, float* __restrict__ GL, int* __restrict__ FM,
    int* __restrict__ FMM, float* __restrict__ outP, float* __restrict__ outSel,
    float* __restrict__ outHx, float* __restrict__ outCx) {
  cg::grid_group grid = cg::this_grid();
  __shared__ float Ws[512][33];   // 67.6 KB
  __shared__ float As[8][32];     // 1 KB (A k-tile)
  __shared__ float qs[512], gvs[512];
  __shared__ float u[128], ps[128], sL[128], kv[128];
  __shared__ float mred, sred, sMult;
  __shared__ int sIdx;

  const int bid = blockIdx.x;
  const int tid = threadIdx.x;
  const int wave = tid >> 6, lane = tid & 63;

  // ---- P0: init state ----
  {
    int i = bid * 512 + tid; // covers kB*kH exactly
    HX[i] = hx0[i];
    CX[i] = cx0[i];
    if (i < kB * kE) DC[i] = dec_in[i];
    if (i < kB) { FM[i] = 1; FMM[i] = 1; }
  }
  grid.sync();

  for (int t = 0; t < kT; ++t) {
    // ======== P1: LSTM gates GEMM (K=256 Wi then K=512 Wh) + activation ========
    if (bid < 256) {
      const int h0 = (bid & 3) * 128;
      const int b0 = (bid >> 2) * 8;
      const int hl = tid & 127, bs = tid >> 7; // bs in 0..3; thread handles b0+bs, b0+bs+4
      float aI[2][4] = {}, aH[2][4] = {};
      for (int k0 = 0; k0 < 768; k0 += 32) {
        const bool isI = (k0 < 256);
        __syncthreads();
        if (tid < 256) { // stage A k-tile: 8 b x 32 k
          int bb = tid >> 5, kk = tid & 31;
          int k = k0 + kk;
          As[bb][kk] = isI ? DC[(size_t)(b0 + bb) * kE + k]
                           : HX[(size_t)(b0 + bb) * kH + (k - 256)];
        }
        for (int idx = tid; idx < 512 * 32; idx += 512) { // stage W k-tile
          int r = idx >> 5, kk = idx & 31;
          int grow = ((r >> 7) << 9) + h0 + (r & 127); // gate*512 + h0 + h_local
          int k = k0 + kk;
          Ws[r][kk] = isI ? Wi[(size_t)grow * kE + k] : Wh[(size_t)grow * kH + (k - 256)];
        }
        __syncthreads();
        if (isI) {
#pragma unroll 4
          for (int kk = 0; kk < 32; ++kk) {
            float a0 = As[bs][kk], a1 = As[bs + 4][kk];
#pragma unroll
            for (int g = 0; g < 4; ++g) {
              float w = Ws[g * 128 + hl][kk];
              aI[0][g] = fmaf(a0, w, aI[0][g]);
              aI[1][g] = fmaf(a1, w, aI[1][g]);
            }
          }
        } else {
#pragma unroll 4
          for (int kk = 0; kk < 32; ++kk) {
            float a0 = As[bs][kk], a1 = As[bs + 4][kk];
#pragma unroll
            for (int g = 0; g < 4; ++g) {
              float w = Ws[g * 128 + hl][kk];
              aH[0][g] = fmaf(a0, w, aH[0][g]);
              aH[1][g] = fmaf(a1, w, aH[1][g]);
            }
          }
        }
      }
      const int h = h0 + hl;
#pragma unroll
      for (int i = 0; i < 2; ++i) {
        int b = b0 + bs + i * 4;
        float ig = ((aI[i][0] + bi[h]) + aH[i][0]) + bh[h];
        float fg = ((aI[i][1] + bi[512 + h]) + aH[i][1]) + bh[512 + h];
        float cgv = ((aI[i][2] + bi[1024 + h]) + aH[i][2]) + bh[1024 + h];
        float og = ((aI[i][3] + bi[1536 + h]) + aH[i][3]) + bh[1536 + h];
        size_t off = (size_t)b * kH + h;
        float cyv = sigf(fg) * CX[off] + sigf(ig) * tanhf(cgv);
        float hyv = sigf(og) * tanhf(cyv);
        CX[off] = cyv;
        HX[off] = hyv;
      }
    }
    grid.sync();

    // ======== P2: qp1 = HX @ gWq^T + gbq (64 blocks, NB=8) ========
    if (bid < 64) {
      const int b0 = bid * 8;
      float acc[8] = {};
      for (int k0 = 0; k0 < 512; k0 += 32) {
        __syncthreads();
        if (tid < 256) {
          int bb = tid >> 5, kk = tid & 31;
          As[bb][kk] = HX[(size_t)(b0 + bb) * kH + k0 + kk];
        }
        for (int idx = tid; idx < 512 * 32; idx += 512) {
          int r = idx >> 5, kk = idx & 31;
          Ws[r][kk] = gWq[(size_t)r * 512 + k0 + kk];
        }
        __syncthreads();
#pragma unroll 4
        for (int kk = 0; kk < 32; ++kk) {
          float w = Ws[tid][kk];
#pragma unroll
          for (int bb = 0; bb < 8; ++bb) acc[bb] = fmaf(As[bb][kk], w, acc[bb]);
        }
      }
      float bv = gbq[tid];
#pragma unroll
      for (int bb = 0; bb < 8; ++bb) QP[(size_t)(b0 + bb) * kH + tid] = acc[bb] + bv;
    }
    grid.sync();

    // ======== P3: att1 + softmax + gl (per-b) ========
    {
      const int b = bid;
      qs[tid] = QP[(size_t)b * kH + tid];
      gvs[tid] = gv[tid];
      __syncthreads();
      for (int r = 0; r < 16; ++r) {
        int s = wave + 8 * r;
        const float* row = EG + ((size_t)s * kB + b) * kH;
        float a = 0.f;
#pragma unroll
        for (int i = 0; i < 8; ++i) {
          int h = lane + 64 * i;
          a = fmaf(gvs[h], tanhf(qs[h] + row[h]), a);
        }
#pragma unroll
        for (int off = 32; off > 0; off >>= 1) a += __shfl_xor(a, off);
        if (lane == 0) u[s] = a;
      }
      __syncthreads();
      if (tid == 0) { float m = u[0]; for (int i = 1; i < 128; ++i) m = fmaxf(m, u[i]); mred = m; }
      __syncthreads();
      if (tid < 128) ps[tid] = expf(u[tid] - mred);
      __syncthreads();
      if (tid == 0) { float s2 = 0.f; for (int i = 0; i < 128; ++i) s2 += ps[i]; sred = s2; }
      __syncthreads();
      if (tid < 128) ps[tid] = ps[tid] / sred;
      __syncthreads();
      float acc = 0.f;
#pragma unroll 4
      for (int s = 0; s < 128; ++s) acc = fmaf(EG[((size_t)s * kB + b) * kH + tid], ps[s], acc);
      GL[(size_t)b * kH + tid] = acc;
    }
    grid.sync();

    // ======== P4: qp2 = GL @ pWq^T + pbq ========
    if (bid < 64) {
      const int b0 = bid * 8;
      float acc[8] = {};
      for (int k0 = 0; k0 < 512; k0 += 32) {
        __syncthreads();
        if (tid < 256) {
          int bb = tid >> 5, kk = tid & 31;
          As[bb][kk] = GL[(size_t)(b0 + bb) * kH + k0 + kk];
        }
        for (int idx = tid; idx < 512 * 32; idx += 512) {
          int r = idx >> 5, kk = idx & 31;
          Ws[r][kk] = pWq[(size_t)r * 512 + k0 + kk];
        }
        __syncthreads();
#pragma unroll 4
        for (int kk = 0; kk < 32; ++kk) {
          float w = Ws[tid][kk];
#pragma unroll
          for (int bb = 0; bb < 8; ++bb) acc[bb] = fmaf(As[bb][kk], w, acc[bb]);
        }
      }
      float bv = pbq[tid];
#pragma unroll
      for (int bb = 0; bb < 8; ++bb) QP[(size_t)(b0 + bb) * kH + tid] = acc[bb] + bv;
    }
    grid.sync();

    // ======== P5: att2 + logits + gumbel + argmax + masks + gather ========
    {
      const int b = bid;
      qs[tid] = QP[(size_t)b * kH + tid];
      gvs[tid] = pv[tid];
      __syncthreads();
      for (int r = 0; r < 16; ++r) {
        int s = wave + 8 * r;
        const float* row = EP + ((size_t)s * kB + b) * kH;
        float a = 0.f;
#pragma unroll
        for (int i = 0; i < 8; ++i) {
          int h = lane + 64 * i;
          a = fmaf(gvs[h], tanhf(qs[h] + row[h]), a);
        }
#pragma unroll
        for (int off = 32; off > 0; off >>= 1) a += __shfl_xor(a, off);
        if (lane == 0) u[s] = a;
      }
      __syncthreads();
      if (tid < 128) sL[tid] = 10.0f * tanhf(u[tid]);
      __syncthreads();
      if (tid == 0) { float m = sL[0]; for (int i = 1; i < 128; ++i) m = fmaxf(m, sL[i]); mred = m; }
      __syncthreads();
      if (tid < 128) ps[tid] = expf(sL[tid] - mred);
      __syncthreads();
      if (tid == 0) { float s2 = 0.f; for (int i = 0; i < 128; ++i) s2 += ps[i]; sred = s2; }
      __syncthreads();
      if (tid < 128) {
        u32 fk0, fk1;
        tf2x32(0u, 42u, 0u, (u32)t, fk0, fk1);
        u32 j = (u32)(b * kS + tid);
        u32 y0, y1;
        tf2x32(fk0, fk1, 0u, j, y0, y1);
        u32 bits = y0 ^ y1; // partitionable 32-bit path
        float f = __uint_as_float(0x3f800000u | (bits >> 9)) - 1.0f;
        float uu = (f > 0.0f) ? f : 1.17549435082228751e-38f;
        float z = -logf(-logf(uu));
        kv[tid] = sL[tid] + z;
      }
      __syncthreads();
      if (tid == 0) {
        float best = kv[0];
        int ia = 0;
        for (int i = 1; i < 128; ++i)
          if (kv[i] > best) { best = kv[i]; ia = i; } // first-index tie-break
        int fm = FM[b], fmm = FMM[b];
        int idx = ia * fm;
        outSel[(size_t)t * kB + b] = (float)idx;
        FM[b] = (idx != 0) ? fm : 0;
        FMM[b] = (t == counts[b]) ? 0 : fmm;
        sIdx = idx;
        sMult = (float)(fm * fmm);
      }
      __syncthreads();
      if (tid < 128) outP[((size_t)b * kT + t) * kS + tid] = (ps[tid] / sred) * sMult;
      if (tid < 256) DC[(size_t)b * kE + tid] = emb[((size_t)sIdx * kB + b) * kE + tid];
    }
    grid.sync();
  }

  // ---- final copy ----
  {
    int i = bid * 512 + tid;
    outHx[i] = HX[i];
    outCx[i] = CX[i];
  }
}

// =================== FALLBACK PATH (proven R15, 4 launches/step) ===================
template <int K, int NB, bool FIRST>
__global__ __launch_bounds__(512) void gemm_v2(const float* __restrict__ A,
                                               const float* __restrict__ W,
                                               const float* __restrict__ bias,
                                               const float* __restrict__ Cin,
                                               float* __restrict__ C, int N) {
  __shared__ float As[NB][K];
  __shared__ float Ws[512][33];
  const int b0 = blockIdx.y * NB;
  const int o0 = blockIdx.x * 512;
  const int tid = threadIdx.x;
  for (int idx = tid; idx < NB * K; idx += 512) {
    int bb = idx / K, k = idx % K;
    As[bb][k] = A[(size_t)(b0 + bb) * K + k];
  }
  float acc[NB] = {};
  for (int k0 = 0; k0 < K; k0 += 32) {
    __syncthreads();
    for (int idx = tid; idx < 512 * 32; idx += 512) {
      int row = idx >> 5, kk = idx & 31;
      Ws[row][kk] = W[(size_t)(o0 + row) * K + k0 + kk];
    }
    __syncthreads();
#pragma unroll 4
    for (int kk = 0; kk < 32; ++kk) {
      float w = Ws[tid][kk];
#pragma unroll
      for (int bb = 0; bb < NB; ++bb) acc[bb] = fmaf(As[bb][k0 + kk], w, acc[bb]);
    }
  }
  float bv = bias[o0 + tid];
#pragma unroll
  for (int bb = 0; bb < NB; ++bb) {
    size_t off = (size_t)(b0 + bb) * N + o0 + tid;
    C[off] = FIRST ? (acc[bb] + bv) : ((Cin[off] + acc[bb]) + bv);
  }
}

__global__ __launch_bounds__(256) void init_k(const float* __restrict__ dec_in,
                                              const float* __restrict__ hx0,
                                              const float* __restrict__ cx0,
                                              float* __restrict__ dec, float* __restrict__ hx,
                                              float* __restrict__ cx, int* __restrict__ fm,
                                              int* __restrict__ fmm) {
  int i = blockIdx.x * blockDim.x + threadIdx.x;
  if (i < kB * kH) { hx[i] = hx0[i]; cx[i] = cx0[i]; }
  if (i < kB * kE) dec[i] = dec_in[i];
  if (i < kB) { fm[i] = 1; fmm[i] = 1; }
}

__global__ __launch_bounds__(256) void lstm_act(const float* __restrict__ gates,
                                                float* __restrict__ hx, float* __restrict__ cx) {
  int i = blockIdx.x * blockDim.x + threadIdx.x;
  int b = i >> 9, h = i & (kH - 1);
  const float* g = gates + (size_t)b * kNG;
  float ig = g[h], fg = g[h + kH], cg = g[h + 2 * kH], og = g[h + 3 * kH];
  float cyv = sigf(fg) * cx[i] + sigf(ig) * tanhf(cg);
  float hyv = sigf(og) * tanhf(cyv);
  cx[i] = cyv;
  hx[i] = hyv;
}

__global__ __launch_bounds__(512) void fused_step(
    const float* __restrict__ EG, const float* __restrict__ EP, const float* __restrict__ gWq,
    const float* __restrict__ gbq, const float* __restrict__ gv, const float* __restrict__ pWq,
    const float* __restrict__ pbq, const float* __restrict__ pv, const float* __restrict__ emb,
    const int* __restrict__ counts, float* __restrict__ HX, float* __restrict__ DC,
    int* __restrict__ fmask, int* __restrict__ fmmask, float* __restrict__ outP,
    float* __restrict__ outSel, int t) {
  __shared__ float Ws[512][33];
  __shared__ float hs[512];
  __shared__ float qs[512];
  __shared__ float gvs[512];
  __shared__ float gls[512];
  __shared__ float u[128], sL[128], ex[128], kv[128];
  __shared__ float mred, sred, sMult;
  __shared__ int sIdx;

  const int b = blockIdx.x;
  const int tid = threadIdx.x;
  const int wave = tid >> 6, lane = tid & 63;

  hs[tid] = HX[(size_t)b * kH + tid];
  gvs[tid] = gv[tid];
  __syncthreads();
  {
    float acc = 0.f;
    for (int k0 = 0; k0 < 512; k0 += 32) {
      __syncthreads();
      for (int idx = tid; idx < 512 * 32; idx += 512) {
        int row = idx >> 5, kk = idx & 31;
        Ws[row][kk] = gWq[(size_t)row * 512 + k0 + kk];
      }
      __syncthreads();
#pragma unroll 8
      for (int kk = 0; kk < 32; ++kk) acc = fmaf(hs[k0 + kk], Ws[tid][kk], acc);
    }
    qs[tid] = acc + gbq[tid];
  }
  __syncthreads();
  for (int r = 0; r < 16; ++r) {
    int s = wave + 8 * r;
    const float* row = EG + ((size_t)s * kB + b) * kH;
    float a = 0.f;
#pragma unroll
    for (int i = 0; i < 8; ++i) {
      int h = lane + 64 * i;
      a = fmaf(gvs[h], tanhf(qs[h] + row[h]), a);
    }
#pragma unroll
    for (int off = 32; off > 0; off >>= 1) a += __shfl_xor(a, off);
    if (lane == 0) u[s] = a;
  }
  __syncthreads();
  if (tid == 0) { float m = u[0]; for (int i = 1; i < 128; ++i) m = fmaxf(m, u[i]); mred = m; }
  __syncthreads();
  if (tid < 128) ex[tid] = expf(u[tid] - mred);
  __syncthreads();
  if (tid == 0) { float s = 0.f; for (int i = 0; i < 128; ++i) s += ex[i]; sred = s; }
  __syncthreads();
  if (tid < 128) ex[tid] = ex[tid] / sred;
  __syncthreads();
  {
    float acc = 0.f;
    for (int s = 0; s < 128; ++s) acc = fmaf(EG[((size_t)s * kB + b) * kH + tid], ex[s], acc);
    gls[tid] = acc;
  }
  __syncthreads();
  {
    float acc = 0.f;
    for (int k0 = 0; k0 < 512; k0 += 32) {
      __syncthreads();
      for (int idx = tid; idx < 512 * 32; idx += 512) {
        int row = idx >> 5, kk = idx & 31;
        Ws[row][kk] = pWq[(size_t)row * 512 + k0 + kk];
      }
      __syncthreads();
#pragma unroll 8
      for (int kk = 0; kk < 32; ++kk) acc = fmaf(gls[k0 + kk], Ws[tid][kk], acc);
    }
    qs[tid] = acc + pbq[tid];
    gvs[tid] = pv[tid];
  }
  __syncthreads();
  for (int r = 0; r < 16; ++r) {
    int s = wave + 8 * r;
    const float* row = EP + ((size_t)s * kB + b) * kH;
    float a = 0.f;
#pragma unroll
    for (int i = 0; i < 8; ++i) {
      int h = lane + 64 * i;
      a = fmaf(gvs[h], tanhf(qs[h] + row[h]), a);
    }
#pragma unroll
    for (int off = 32; off > 0; off >>= 1) a += __shfl_xor(a, off);
    if (lane == 0) u[s] = a;
  }
  __syncthreads();
  if (tid < 128) sL[tid] = 10.0f * tanhf(u[tid]);
  __syncthreads();
  if (tid == 0) { float m = sL[0]; for (int i = 1; i < 128; ++i) m = fmaxf(m, sL[i]); mred = m; }
  __syncthreads();
  if (tid < 128) ex[tid] = expf(sL[tid] - mred);
  __syncthreads();
  if (tid == 0) { float s = 0.f; for (int i = 0; i < 128; ++i) s += ex[i]; sred = s; }
  __syncthreads();
  if (tid < 128) {
    u32 fk0, fk1;
    tf2x32(0u, 42u, 0u, (u32)t, fk0, fk1);
    u32 j = (u32)(b * kS + tid);
    u32 y0, y1;
    tf2x32(fk0, fk1, 0u, j, y0, y1);
    u32 bits = y0 ^ y1;
    float f = __uint_as_float(0x3f800000u | (bits >> 9)) - 1.0f;
    float uu = (f > 0.0f) ? f : 1.17549435082228751e-38f;
    float z = -logf(-logf(uu));
    kv[tid] = sL[tid] + z;
  }
  __syncthreads();
  if (tid == 0) {
    float best = kv[0];
    int ia = 0;
    for (int i = 1; i < 128; ++i)
      if (kv[i] > best) { best = kv[i]; ia = i; }
    int fm = fmask[b], fmm = fmmask[b];
    int idx = ia * fm;
    outSel[(size_t)t * kB + b] = (float)idx;
    fmask[b] = (idx != 0) ? fm : 0;
    fmmask[b] = (t == counts[b]) ? 0 : fmm;
    sIdx = idx;
    sMult = (float)(fm * fmm);
  }
  __syncthreads();
  if (tid < 128) outP[((size_t)b * kT + t) * kS + tid] = (ex[tid] / sred) * sMult;
  if (tid < 256) DC[(size_t)b * kE + tid] = emb[((size_t)sIdx * kB + b) * kE + tid];
}

__global__ __launch_bounds__(256) void final_copy(const float* __restrict__ hx,
                                                  const float* __restrict__ cx,
                                                  float* __restrict__ o2, float* __restrict__ o3) {
  int i = blockIdx.x * blockDim.x + threadIdx.x;
  if (i < kB * kH) { o2[i] = hx[i]; o3[i] = cx[i]; }
}

extern "C" void kernel_launch(void* const* d_in, const int* in_sizes, int n_in, void* d_out,
                              int out_size, void* d_ws, size_t ws_size, hipStream_t stream) {
  const float* dec_in = (const float*)d_in[0];
  const float* emb = (const float*)d_in[1];
  const float* hx0 = (const float*)d_in[2];
  const float* cx0 = (const float*)d_in[3];
  const float* ctx = (const float*)d_in[4];
  const int* counts = (const int*)d_in[5];
  const float* Wi = (const float*)d_in[7];
  const float* bi = (const float*)d_in[8];
  const float* Wh = (const float*)d_in[9];
  const float* bh = (const float*)d_in[10];
  const float* gWq = (const float*)d_in[11];
  const float* gbq = (const float*)d_in[12];
  const float* gWr = (const float*)d_in[13];
  const float* gbr = (const float*)d_in[14];
  const float* gv = (const float*)d_in[15];
  const float* pWq = (const float*)d_in[16];
  const float* pbq = (const float*)d_in[17];
  const float* pWr = (const float*)d_in[18];
  const float* pbr = (const float*)d_in[19];
  const float* pv = (const float*)d_in[20];

  float* out = (float*)d_out;
  float* outP = out;                          // (B*T, S)
  float* outSel = out + (size_t)kB * kT * kS; // (T, B)
  float* outHx = outSel + (size_t)kT * kB;    // (B, H)
  float* outCx = outHx + (size_t)kB * kH;     // (B, H)

  if (ws_size < WS_FLOATS * sizeof(float)) {
    double wsMB = (double)ws_size / (1024.0 * 1024.0);
    if (wsMB > 80000.0) wsMB = 80000.0;
    hipLaunchKernelGGL(sentinel_k, dim3((kT * kB + 255) / 256), dim3(256), 0, stream, outSel,
                       (float)(1000.0 + wsMB));
    return;
  }

  float* base = (float*)d_ws;
  float* EG = base + OFF_EG;
  float* EP = base + OFF_EP;
  float* QP = base + OFF_QP;
  float* GL = base + OFF_GL;
  float* G  = base + OFF_G;
  float* HX = base + OFF_HX;
  float* CX = base + OFF_CX;
  float* DC = base + OFF_DC;
  int* FM  = (int*)(base + OFF_FM);
  int* FMM = (int*)(base + OFF_FMM);

  hipLaunchKernelGGL(precompute_e, dim3(kS * kB / 8), dim3(512), 0, stream, ctx, gWr, gbr, pWr,
                     pbr, EG, EP);

  // ---- try cooperative megakernel ----
  void* args[] = {(void*)&EG,  (void*)&EP,  (void*)&Wi,  (void*)&bi,   (void*)&Wh,
                  (void*)&bh,  (void*)&gWq, (void*)&gbq, (void*)&gv,   (void*)&pWq,
                  (void*)&pbq, (void*)&pv,  (void*)&emb, (void*)&counts, (void*)&dec_in,
                  (void*)&hx0, (void*)&cx0, (void*)&HX,  (void*)&CX,   (void*)&DC,
                  (void*)&QP,  (void*)&GL,  (void*)&FM,  (void*)&FMM,  (void*)&outP,
                  (void*)&outSel, (void*)&outHx, (void*)&outCx};
  hipError_t st = hipLaunchCooperativeKernel((const void*)mega_k, dim3(512), dim3(512), args, 0,
                                             stream);
  if (st == hipSuccess) return;

  // ---- fallback: proven R15 path ----
  hipLaunchKernelGGL(init_k, dim3(kB * kH / 256), dim3(256), 0, stream, dec_in, hx0, cx0, DC, HX,
                     CX, FM, FMM);
  for (int t = 0; t < kT; ++t) {
    hipLaunchKernelGGL((gemm_v2<256, 8, true>), dim3(4, 64), dim3(512), 0, stream, DC, Wi, bi,
                       (const float*)nullptr, G, kNG);
    hipLaunchKernelGGL((gemm_v2<512, 8, false>), dim3(4, 64), dim3(512), 0, stream, HX, Wh, bh, G,
                       G, kNG);
    hipLaunchKernelGGL(lstm_act, dim3(kB * kH / 256), dim3(256), 0, stream, G, HX, CX);
    hipLaunchKernelGGL(fused_step, dim3(kB), dim3(512), 0, stream, EG, EP, gWq, gbq, gv, pWq, pbq,
                       pv, emb, counts, HX, DC, FM, FMM, outP, outSel, t);
  }
  hipLaunchKernelGGL(final_copy, dim3(kB * kH / 256), dim3(256), 0, stream, HX, CX, outHx, outCx);
}

// Round 18
// 38470.657 us; speedup vs baseline: 2.3814x; 2.3814x over previous
//
#include <hip/hip_runtime.h>
#include <stdint.h>
#include <math.h>

typedef unsigned int u32;

constexpr int kB = 512, kS = 128, kH = 512, kE = 256, kT = 100;
constexpr int kNG = 4 * kH; // 2048

// ---- ws layout (f32 elements) ----
constexpr size_t SZ_E = (size_t)kS * kB * kH; // 33,554,432
constexpr size_t OFF_EG  = 0;                              // EG [s][b][h]
constexpr size_t OFF_EP  = OFF_EG + SZ_E;                  // EP [s][b][h]
constexpr size_t OFF_U   = OFF_EP + SZ_E;
constexpr size_t OFF_P   = OFF_U + (size_t)kB * kS;
constexpr size_t OFF_QP  = OFF_P + (size_t)kB * kS;        // kB*kH
constexpr size_t OFF_GL  = OFF_QP + (size_t)kB * kH;       // kB*kH
constexpr size_t OFF_G   = OFF_GL + (size_t)kB * kH;       // kB*kNG (unused now)
constexpr size_t OFF_HX  = OFF_G + (size_t)kB * kNG;       // kB*kH
constexpr size_t OFF_CX  = OFF_HX + (size_t)kB * kH;       // kB*kH
constexpr size_t OFF_DC  = OFF_CX + (size_t)kB * kH;       // kB*kE
constexpr size_t OFF_FM  = OFF_DC + (size_t)kB * kE;       // kB ints
constexpr size_t OFF_FMM = OFF_FM + kB;
constexpr size_t WS_FLOATS = OFF_FMM + kB;                 // ≈265 MiB (PROVEN available)

// ---------------- sentinel (bail only) ----------------
__global__ __launch_bounds__(256) void sentinel_k(float* __restrict__ outSel, float val) {
  int i = blockIdx.x * blockDim.x + threadIdx.x;
  if (i < kT * kB) outSel[i] = val;
}

// ---------------- threefry2x32 (exact JAX) ----------------
__device__ __forceinline__ u32 rotl32(u32 v, int d) { return (v << d) | (v >> (32 - d)); }

__device__ __forceinline__ void tf2x32(u32 k0, u32 k1, u32 x0, u32 x1, u32& o0, u32& o1) {
  u32 ks2 = k0 ^ k1 ^ 0x1BD11BDAu;
  x0 += k0; x1 += k1;
#define RND_(r) { x0 += x1; x1 = rotl32(x1, r); x1 ^= x0; }
  RND_(13) RND_(15) RND_(26) RND_(6)   x0 += k1;  x1 += ks2 + 1u;
  RND_(17) RND_(29) RND_(16) RND_(24)  x0 += ks2; x1 += k0 + 2u;
  RND_(13) RND_(15) RND_(26) RND_(6)   x0 += k0;  x1 += k1 + 3u;
  RND_(17) RND_(29) RND_(16) RND_(24)  x0 += k1;  x1 += ks2 + 4u;
  RND_(13) RND_(15) RND_(26) RND_(6)   x0 += ks2; x1 += k0 + 5u;
#undef RND_
  o0 = x0; o1 = x1;
}

__device__ __forceinline__ float sigf(float x) { return 1.0f / (1.0f + expf(-x)); }

// ------- E precompute (unchanged, proven) -------
__global__ __launch_bounds__(512) void precompute_e(const float* __restrict__ ctx,
                                                    const float* __restrict__ Wg,
                                                    const float* __restrict__ bg,
                                                    const float* __restrict__ Wp,
                                                    const float* __restrict__ bp,
                                                    float* __restrict__ EG,
                                                    float* __restrict__ EP) {
  __shared__ float ctxs[8][512];
  __shared__ float Wgs[512][33];
  __shared__ float Wps[512][33];
  const int tid = threadIdx.x;
  const size_t m0 = (size_t)blockIdx.x * 8;
  for (int idx = tid; idx < 8 * 512; idx += 512) {
    ctxs[idx >> 9][idx & 511] = ctx[(m0 + (idx >> 9)) * 512 + (idx & 511)];
  }
  float accg[8] = {}, accp[8] = {};
  for (int k0 = 0; k0 < 512; k0 += 32) {
    __syncthreads();
    for (int idx = tid; idx < 512 * 32; idx += 512) {
      int row = idx >> 5, kk = idx & 31;
      Wgs[row][kk] = Wg[(size_t)row * 512 + k0 + kk];
      Wps[row][kk] = Wp[(size_t)row * 512 + k0 + kk];
    }
    __syncthreads();
#pragma unroll 4
    for (int kk = 0; kk < 32; ++kk) {
      float wg = Wgs[tid][kk], wp = Wps[tid][kk];
#pragma unroll
      for (int mi = 0; mi < 8; ++mi) {
        float a = ctxs[mi][k0 + kk];
        accg[mi] = fmaf(a, wg, accg[mi]);
        accp[mi] = fmaf(a, wp, accp[mi]);
      }
    }
  }
  float bgv = bg[tid], bpv = bp[tid];
#pragma unroll
  for (int mi = 0; mi < 8; ++mi) {
    size_t m = m0 + mi;
    EG[m * 512 + tid] = accg[mi] + bgv;
    EP[m * 512 + tid] = accp[mi] + bpv;
  }
}

// ---------------- init state ----------------
__global__ __launch_bounds__(256) void init_k(const float* __restrict__ dec_in,
                                              const float* __restrict__ hx0,
                                              const float* __restrict__ cx0,
                                              float* __restrict__ dec, float* __restrict__ hx,
                                              float* __restrict__ cx, int* __restrict__ fm,
                                              int* __restrict__ fmm) {
  int i = blockIdx.x * blockDim.x + threadIdx.x;
  if (i < kB * kH) { hx[i] = hx0[i]; cx[i] = cx0[i]; }
  if (i < kB * kE) dec[i] = dec_in[i];
  if (i < kB) { fm[i] = 1; fmm[i] = 1; }
}

// ======= lstm_fused: Wi-GEMM + Wh-GEMM + LSTM activation (verified as mega_k P1) =======
// grid 256 = (64 b-tiles of 8) x (4 h-tiles of 128); block 512
__global__ __launch_bounds__(512) void lstm_fused(
    const float* __restrict__ DC, const float* __restrict__ Wi, const float* __restrict__ bi,
    const float* __restrict__ Wh, const float* __restrict__ bh, float* __restrict__ HX,
    float* __restrict__ CX) {
  __shared__ float Ws[512][33];
  __shared__ float As[8][32];
  const int bid = blockIdx.x;
  const int tid = threadIdx.x;
  const int h0 = (bid & 3) * 128;
  const int b0 = (bid >> 2) * 8;
  const int hl = tid & 127, bs = tid >> 7; // bs in 0..3; thread handles b0+bs, b0+bs+4
  float aI[2][4] = {}, aH[2][4] = {};
  for (int k0 = 0; k0 < 768; k0 += 32) {
    const bool isI = (k0 < 256);
    __syncthreads();
    if (tid < 256) {
      int bb = tid >> 5, kk = tid & 31;
      int k = k0 + kk;
      As[bb][kk] = isI ? DC[(size_t)(b0 + bb) * kE + k] : HX[(size_t)(b0 + bb) * kH + (k - 256)];
    }
    for (int idx = tid; idx < 512 * 32; idx += 512) {
      int r = idx >> 5, kk = idx & 31;
      int grow = ((r >> 7) << 9) + h0 + (r & 127); // gate*512 + h
      int k = k0 + kk;
      Ws[r][kk] = isI ? Wi[(size_t)grow * kE + k] : Wh[(size_t)grow * kH + (k - 256)];
    }
    __syncthreads();
    if (isI) {
#pragma unroll 4
      for (int kk = 0; kk < 32; ++kk) {
        float a0 = As[bs][kk], a1 = As[bs + 4][kk];
#pragma unroll
        for (int g = 0; g < 4; ++g) {
          float w = Ws[g * 128 + hl][kk];
          aI[0][g] = fmaf(a0, w, aI[0][g]);
          aI[1][g] = fmaf(a1, w, aI[1][g]);
        }
      }
    } else {
#pragma unroll 4
      for (int kk = 0; kk < 32; ++kk) {
        float a0 = As[bs][kk], a1 = As[bs + 4][kk];
#pragma unroll
        for (int g = 0; g < 4; ++g) {
          float w = Ws[g * 128 + hl][kk];
          aH[0][g] = fmaf(a0, w, aH[0][g]);
          aH[1][g] = fmaf(a1, w, aH[1][g]);
        }
      }
    }
  }
  const int h = h0 + hl;
#pragma unroll
  for (int i = 0; i < 2; ++i) {
    int b = b0 + bs + i * 4;
    float ig = ((aI[i][0] + bi[h]) + aH[i][0]) + bh[h];
    float fg = ((aI[i][1] + bi[512 + h]) + aH[i][1]) + bh[512 + h];
    float cgv = ((aI[i][2] + bi[1024 + h]) + aH[i][2]) + bh[1024 + h];
    float og = ((aI[i][3] + bi[1536 + h]) + aH[i][3]) + bh[1536 + h];
    size_t off = (size_t)b * kH + h;
    float cyv = sigf(fg) * CX[off] + sigf(ig) * tanhf(cgv);
    float hyv = sigf(og) * tanhf(cyv);
    CX[off] = cyv;
    HX[off] = hyv;
  }
}

// ======= fused_step v2: qp via direct W row reads (no LDS staging, no barriers) =======
__global__ __launch_bounds__(512, 8) void fused_step(
    const float* __restrict__ EG, const float* __restrict__ EP, const float* __restrict__ gWq,
    const float* __restrict__ gbq, const float* __restrict__ gv, const float* __restrict__ pWq,
    const float* __restrict__ pbq, const float* __restrict__ pv, const float* __restrict__ emb,
    const int* __restrict__ counts, float* __restrict__ HX, float* __restrict__ DC,
    int* __restrict__ fmask, int* __restrict__ fmmask, float* __restrict__ outP,
    float* __restrict__ outSel, int t) {
  __shared__ float hs[512];
  __shared__ float qs[512];
  __shared__ float gvs[512];
  __shared__ float gls[512];
  __shared__ float u[128], sL[128], ex[128], kv[128];
  __shared__ float mred, sred, sMult;
  __shared__ int sIdx;

  const int b = blockIdx.x;
  const int tid = threadIdx.x;
  const int wave = tid >> 6, lane = tid & 63;

  hs[tid] = HX[(size_t)b * kH + tid];
  gvs[tid] = gv[tid];
  __syncthreads();

  // ---- qp1 = hs @ gWq^T + gbq : per-thread row read, ascending-k fmaf (bit-exact) ----
  {
    float acc = 0.f;
    const float4* wrow = (const float4*)(gWq + (size_t)tid * 512);
#pragma unroll 8
    for (int k = 0; k < 128; ++k) {
      float4 w = wrow[k];
      acc = fmaf(hs[4 * k + 0], w.x, acc);
      acc = fmaf(hs[4 * k + 1], w.y, acc);
      acc = fmaf(hs[4 * k + 2], w.z, acc);
      acc = fmaf(hs[4 * k + 3], w.w, acc);
    }
    qs[tid] = acc + gbq[tid];
  }
  __syncthreads();

  // ---- att1 u[s]: wave-per-s, lanes split h, shuffle reduce (R15 order) ----
  for (int r = 0; r < 16; ++r) {
    int s = wave + 8 * r;
    const float* row = EG + ((size_t)s * kB + b) * kH;
    float a = 0.f;
#pragma unroll
    for (int i = 0; i < 8; ++i) {
      int h = lane + 64 * i;
      a = fmaf(gvs[h], tanhf(qs[h] + row[h]), a);
    }
#pragma unroll
    for (int off = 32; off > 0; off >>= 1) a += __shfl_xor(a, off);
    if (lane == 0) u[s] = a;
  }
  __syncthreads();

  if (tid == 0) { float m = u[0]; for (int i = 1; i < 128; ++i) m = fmaxf(m, u[i]); mred = m; }
  __syncthreads();
  if (tid < 128) ex[tid] = expf(u[tid] - mred);
  __syncthreads();
  if (tid == 0) { float s = 0.f; for (int i = 0; i < 128; ++i) s += ex[i]; sred = s; }
  __syncthreads();
  if (tid < 128) ex[tid] = ex[tid] / sred;
  __syncthreads();

  // ---- gl[h] = serial_s fmaf(EG[s][b][h], P[s]) (R15 order) ----
  {
    float acc = 0.f;
    for (int s = 0; s < 128; ++s) acc = fmaf(EG[((size_t)s * kB + b) * kH + tid], ex[s], acc);
    gls[tid] = acc;
  }
  __syncthreads();

  // ---- qp2 = gls @ pWq^T + pbq ----
  {
    float acc = 0.f;
    const float4* wrow = (const float4*)(pWq + (size_t)tid * 512);
#pragma unroll 8
    for (int k = 0; k < 128; ++k) {
      float4 w = wrow[k];
      acc = fmaf(gls[4 * k + 0], w.x, acc);
      acc = fmaf(gls[4 * k + 1], w.y, acc);
      acc = fmaf(gls[4 * k + 2], w.z, acc);
      acc = fmaf(gls[4 * k + 3], w.w, acc);
    }
    qs[tid] = acc + pbq[tid];
    gvs[tid] = pv[tid];
  }
  __syncthreads();

  // ---- att2 u[s] on EP ----
  for (int r = 0; r < 16; ++r) {
    int s = wave + 8 * r;
    const float* row = EP + ((size_t)s * kB + b) * kH;
    float a = 0.f;
#pragma unroll
    for (int i = 0; i < 8; ++i) {
      int h = lane + 64 * i;
      a = fmaf(gvs[h], tanhf(qs[h] + row[h]), a);
    }
#pragma unroll
    for (int off = 32; off > 0; off >>= 1) a += __shfl_xor(a, off);
    if (lane == 0) u[s] = a;
  }
  __syncthreads();

  // ---- logits, softmax, gumbel, argmax, masks, gather (R13/R15 semantics) ----
  if (tid < 128) sL[tid] = 10.0f * tanhf(u[tid]);
  __syncthreads();
  if (tid == 0) { float m = sL[0]; for (int i = 1; i < 128; ++i) m = fmaxf(m, sL[i]); mred = m; }
  __syncthreads();
  if (tid < 128) ex[tid] = expf(sL[tid] - mred);
  __syncthreads();
  if (tid == 0) { float s = 0.f; for (int i = 0; i < 128; ++i) s += ex[i]; sred = s; }
  __syncthreads();
  if (tid < 128) {
    u32 fk0, fk1;
    tf2x32(0u, 42u, 0u, (u32)t, fk0, fk1);
    u32 j = (u32)(b * kS + tid);
    u32 y0, y1;
    tf2x32(fk0, fk1, 0u, j, y0, y1);
    u32 bits = y0 ^ y1; // partitionable 32-bit path
    float f = __uint_as_float(0x3f800000u | (bits >> 9)) - 1.0f;
    float uu = (f > 0.0f) ? f : 1.17549435082228751e-38f;
    float z = -logf(-logf(uu));
    kv[tid] = sL[tid] + z;
  }
  __syncthreads();
  if (tid == 0) {
    float best = kv[0];
    int ia = 0;
    for (int i = 1; i < 128; ++i)
      if (kv[i] > best) { best = kv[i]; ia = i; } // first-index tie-break
    int fm = fmask[b], fmm = fmmask[b];
    int idx = ia * fm;
    outSel[(size_t)t * kB + b] = (float)idx;
    fmask[b] = (idx != 0) ? fm : 0;
    fmmask[b] = (t == counts[b]) ? 0 : fmm;
    sIdx = idx;
    sMult = (float)(fm * fmm);
  }
  __syncthreads();
  if (tid < 128) outP[((size_t)b * kT + t) * kS + tid] = (ex[tid] / sred) * sMult;
  if (tid < 256) DC[(size_t)b * kE + tid] = emb[((size_t)sIdx * kB + b) * kE + tid];
}

// ---------------- final hx/cx copy ----------------
__global__ __launch_bounds__(256) void final_copy(const float* __restrict__ hx,
                                                  const float* __restrict__ cx,
                                                  float* __restrict__ o2, float* __restrict__ o3) {
  int i = blockIdx.x * blockDim.x + threadIdx.x;
  if (i < kB * kH) { o2[i] = hx[i]; o3[i] = cx[i]; }
}

extern "C" void kernel_launch(void* const* d_in, const int* in_sizes, int n_in, void* d_out,
                              int out_size, void* d_ws, size_t ws_size, hipStream_t stream) {
  const float* dec_in = (const float*)d_in[0];
  const float* emb = (const float*)d_in[1];
  const float* hx0 = (const float*)d_in[2];
  const float* cx0 = (const float*)d_in[3];
  const float* ctx = (const float*)d_in[4];
  const int* counts = (const int*)d_in[5];
  const float* Wi = (const float*)d_in[7];
  const float* bi = (const float*)d_in[8];
  const float* Wh = (const float*)d_in[9];
  const float* bh = (const float*)d_in[10];
  const float* gWq = (const float*)d_in[11];
  const float* gbq = (const float*)d_in[12];
  const float* gWr = (const float*)d_in[13];
  const float* gbr = (const float*)d_in[14];
  const float* gv = (const float*)d_in[15];
  const float* pWq = (const float*)d_in[16];
  const float* pbq = (const float*)d_in[17];
  const float* pWr = (const float*)d_in[18];
  const float* pbr = (const float*)d_in[19];
  const float* pv = (const float*)d_in[20];

  float* out = (float*)d_out;
  float* outP = out;                          // (B*T, S)
  float* outSel = out + (size_t)kB * kT * kS; // (T, B)
  float* outHx = outSel + (size_t)kT * kB;    // (B, H)
  float* outCx = outHx + (size_t)kB * kH;     // (B, H)

  if (ws_size < WS_FLOATS * sizeof(float)) {
    double wsMB = (double)ws_size / (1024.0 * 1024.0);
    if (wsMB > 80000.0) wsMB = 80000.0;
    hipLaunchKernelGGL(sentinel_k, dim3((kT * kB + 255) / 256), dim3(256), 0, stream, outSel,
                       (float)(1000.0 + wsMB));
    return;
  }

  float* base = (float*)d_ws;
  float* EG = base + OFF_EG;
  float* EP = base + OFF_EP;
  float* HX = base + OFF_HX;
  float* CX = base + OFF_CX;
  float* DC = base + OFF_DC;
  int* FM  = (int*)(base + OFF_FM);
  int* FMM = (int*)(base + OFF_FMM);

  hipLaunchKernelGGL(precompute_e, dim3(kS * kB / 8), dim3(512), 0, stream, ctx, gWr, gbr, pWr,
                     pbr, EG, EP);
  hipLaunchKernelGGL(init_k, dim3(kB * kH / 256), dim3(256), 0, stream, dec_in, hx0, cx0, DC, HX,
                     CX, FM, FMM);

  for (int t = 0; t < kT; ++t) {
    hipLaunchKernelGGL(lstm_fused, dim3(256), dim3(512), 0, stream, DC, Wi, bi, Wh, bh, HX, CX);
    hipLaunchKernelGGL(fused_step, dim3(kB), dim3(512), 0, stream, EG, EP, gWq, gbq, gv, pWq, pbq,
                       pv, emb, counts, HX, DC, FM, FMM, outP, outSel, t);
  }
  hipLaunchKernelGGL(final_copy, dim3(kB * kH / 256), dim3(256), 0, stream, HX, CX, outHx, outCx);
}